// Round 2
// 1377.396 us; speedup vs baseline: 1.1178x; 1.1178x over previous
//
#include <hip/hip_runtime.h>
#include <cstddef>

#define NT   8
#define NN   100000
#define NE   1600000
#define DIN  64
#define DH   64
#define DE   16
#define FLAT 4096
#define BN   1024

__device__ __forceinline__ void atomAdd(float* p, float v) { unsafeAtomicAdd(p, v); }

__device__ __forceinline__ void fma4(float4& a, float s, const float4& w) {
  a.x = fmaf(s, w.x, a.x); a.y = fmaf(s, w.y, a.y);
  a.z = fmaf(s, w.z, a.z); a.w = fmaf(s, w.w, a.w);
}

// ---------------- init: w[1]=init_w, zero k/acc1, zero cnt -------------------------
__global__ void k_init(const float* __restrict__ init_w, float* __restrict__ wbuf,
                       float* __restrict__ kbuf, float* __restrict__ acc1,
                       int* __restrict__ cnt) {
  int i = blockIdx.x * blockDim.x + threadIdx.x;          // 32768 threads
  if (i < FLAT) wbuf[FLAT + i] = init_w[i];
  if (i < 8 * FLAT) kbuf[i] = 0.f;
  if (i < 2 * BN) acc1[i] = 0.f;
  for (int n = i; n < NN; n += gridDim.x * blockDim.x) cnt[n] = 0;
}

// ---------------- ODE phase A: acc1[pe] += win @ w1 (tile-split, atomics) ----------
__global__ __launch_bounds__(256) void k_odeA(
    const float* __restrict__ w1, const float* __restrict__ wbase,
    const float* __restrict__ kbase, float c0, float c1, float c2, float c3,
    float* __restrict__ acc_dst, float* __restrict__ acc_zero,
    float* __restrict__ k_zero, float* __restrict__ w_store) {
  __shared__ float win[256];
  __shared__ float red[256];
  const int t = threadIdx.x;
  const int ic = blockIdx.x & 15, jc = blockIdx.x >> 4;   // 16 i-chunks x 16 j-chunks
  const int i0 = ic * 256;
  if (t < 16) k_zero[blockIdx.x * 16 + t] = 0.f;          // 256*16 = 4096
  if (t >= 16 && t < 20) acc_zero[blockIdx.x * 4 + (t - 16)] = 0.f;  // 256*4 = 1024
  {
    int i = i0 + t;
    float v = wbase[i] + c0 * kbase[i] + c1 * kbase[FLAT + i]
            + c2 * kbase[2 * FLAT + i] + c3 * kbase[3 * FLAT + i];
    win[t] = v;
    if (w_store != nullptr && jc == 0) w_store[i] = v;    // single-writer w_next
  }
  __syncthreads();
  const int jl = t & 63, ig = t >> 6;
  const int j = jc * 64 + jl;
  const float* wp = w1 + (size_t)(i0 + ig * 64) * BN + j;
  float acc = 0.f;
#pragma unroll 8
  for (int ii = 0; ii < 64; ++ii)
    acc = fmaf(win[ig * 64 + ii], wp[(size_t)ii * BN], acc);
  red[t] = acc;
  __syncthreads();
  if (t < 64) {
    float s = red[t] + red[t + 64] + red[t + 128] + red[t + 192];
    atomAdd(&acc_dst[jc * 64 + t], s);
  }
}

// ---------------- ODE phase B: k_dst += tanh(acc1+b1) @ w2 (+b2 once) --------------
__global__ __launch_bounds__(256) void k_odeB(
    const float* __restrict__ w2, const float* __restrict__ acc_src,
    const float* __restrict__ b1, const float* __restrict__ b2,
    float* __restrict__ k_dst) {
  __shared__ float tl[64];
  const int t = threadIdx.x;
  const int ic = blockIdx.x & 15, jc = blockIdx.x >> 4;
  const int i0 = ic * 64;
  if (t < 64) tl[t] = tanhf(acc_src[i0 + t] + b1[i0 + t]);
  __syncthreads();
  const int j = jc * 256 + t;
  const float* wp = w2 + (size_t)i0 * FLAT + j;
  float acc = (ic == 0) ? b2[j] : 0.f;
#pragma unroll 8
  for (int ii = 0; ii < 64; ++ii)
    acc = fmaf(tl[ii], wp[(size_t)ii * FLAT], acc);
  atomAdd(&k_dst[j], acc);
}

// ---------------- final W_T ---------------------------------------------------------
__global__ void k_final(const float* __restrict__ w0, const float* __restrict__ k0,
                        float* __restrict__ WT) {
  int i = blockIdx.x * blockDim.x + threadIdx.x;
  if (i < FLAT) {
    const float h8 = (1.0f / 7.0f) * 0.125f;
    WT[i] = w0[i] + h8 * (k0[i] + 3.f * (k0[FLAT + i] + k0[2 * FLAT + i]) + k0[3 * FLAT + i]);
  }
}

// ---------------- CSR build: histogram by col --------------------------------------
__global__ void k_hist(const int* __restrict__ ei, int* __restrict__ cnt) {
  int e = blockIdx.x * blockDim.x + threadIdx.x;
  if (e < NE) atomicAdd(&cnt[ei[NE + e]], 1);
}

// ---------------- scan step 1: per-block exclusive scan of cnt ---------------------
__global__ __launch_bounds__(256) void k_scan1(const int* __restrict__ cnt,
                                               int* __restrict__ offs,
                                               int* __restrict__ bsum) {
  __shared__ int s[256];
  const int t = threadIdx.x;
  const int i = blockIdx.x * 256 + t;
  int v = (i < NN) ? cnt[i] : 0;
  s[t] = v;
  __syncthreads();
  for (int off = 1; off < 256; off <<= 1) {
    int x = (t >= off) ? s[t - off] : 0;
    __syncthreads();
    s[t] += x;
    __syncthreads();
  }
  if (i < NN) offs[i] = s[t] - v;          // exclusive
  if (t == 255) bsum[blockIdx.x] = s[255];
}

// ---------------- scan step 2: scan of block sums (single block) -------------------
__global__ __launch_bounds__(512) void k_scan2(int* __restrict__ bsum,
                                               int* __restrict__ bofs, int nblk) {
  __shared__ int s[512];
  const int t = threadIdx.x;
  int v = (t < nblk) ? bsum[t] : 0;
  s[t] = v;
  __syncthreads();
  for (int off = 1; off < 512; off <<= 1) {
    int x = (t >= off) ? s[t - off] : 0;
    __syncthreads();
    s[t] += x;
    __syncthreads();
  }
  if (t < nblk) bofs[t] = s[t] - v;        // exclusive
}

// ---------------- scan step 3: add block offsets, init cursors, dis ----------------
__global__ __launch_bounds__(256) void k_scan3(const int* __restrict__ cnt,
                                               int* __restrict__ offs,
                                               const int* __restrict__ bofs,
                                               int* __restrict__ cur,
                                               float* __restrict__ dis) {
  const int i = blockIdx.x * 256 + threadIdx.x;
  if (i < NN) {
    int o = offs[i] + bofs[i >> 8];
    offs[i] = o;
    cur[i] = o;
    dis[i] = rsqrtf((float)(cnt[i] + 1));  // +1 self-loop, deg >= 1 always
  }
  if (i == 0) offs[NN] = NE;
}

// ---------------- CSR fill: csr[pos] = (row, edge_id), bucketed by col -------------
__global__ void k_fill(const int* __restrict__ ei, int* __restrict__ cur,
                       int2* __restrict__ csr) {
  int e = blockIdx.x * blockDim.x + threadIdx.x;
  if (e < NE) {
    int row = ei[e], col = ei[NE + e];
    int pos = atomicAdd(&cur[col], 1);
    csr[pos] = make_int2(row, e);
  }
}

// ---------------- xw = x_last @ W_T : 16 lanes/node, 4 nodes/thread-group ----------
__global__ __launch_bounds__(256) void k_xw(
    const float* __restrict__ x_last, const float* __restrict__ WT,
    float* __restrict__ xw) {
  __shared__ float wt[FLAT];
  for (int i = threadIdx.x; i < FLAT; i += 256) wt[i] = WT[i];
  __syncthreads();
  const int lane = threadIdx.x & 15;
  const int grp = threadIdx.x >> 4;
  const int n0 = blockIdx.x * 64 + grp * 4;
  if (n0 >= NN) return;
  const int nvalid = (NN - n0 < 4) ? (NN - n0) : 4;
  const float4* xp[4];
#pragma unroll
  for (int m = 0; m < 4; ++m) {
    int n = (m < nvalid) ? (n0 + m) : n0;
    xp[m] = (const float4*)(x_last + (size_t)n * 64);
  }
  float4 acc[4];
#pragma unroll
  for (int m = 0; m < 4; ++m) acc[m] = make_float4(0.f, 0.f, 0.f, 0.f);
#pragma unroll
  for (int q = 0; q < 16; ++q) {
    const float* wr = &wt[(q * 4) * 64 + lane * 4];
    float4 w0 = *(const float4*)&wr[0];
    float4 w1 = *(const float4*)&wr[64];
    float4 w2 = *(const float4*)&wr[128];
    float4 w3 = *(const float4*)&wr[192];
#pragma unroll
    for (int m = 0; m < 4; ++m) {
      float4 x4 = xp[m][q];          // same addr across 16 lanes -> broadcast
      fma4(acc[m], x4.x, w0); fma4(acc[m], x4.y, w1);
      fma4(acc[m], x4.z, w2); fma4(acc[m], x4.w, w3);
    }
  }
  for (int m = 0; m < nvalid; ++m)
    *(float4*)&xw[(size_t)(n0 + m) * 64 + lane * 4] = acc[m];
}

// ---------------- pass 1: h[col] = relu(sum_e norm*xw[row] + d^2*xw[col]) ----------
// one 64-lane wave per node, lane = feature index; pure gather, no atomics.
__global__ __launch_bounds__(256) void k_gh(
    const int* __restrict__ offs, const int2* __restrict__ csr,
    const float* __restrict__ dis, const float* __restrict__ xw,
    float* __restrict__ h) {
  const int node = blockIdx.x * 4 + (threadIdx.x >> 6);
  const int lane = threadIdx.x & 63;
  if (node >= NN) return;
  const int off0 = offs[node], off1 = offs[node + 1];
  const float d = dis[node];
  float acc = d * d * xw[(size_t)node * 64 + lane];
  int e = off0;
  for (; e + 1 < off1; e += 2) {
    int2 c0 = csr[e], c1 = csr[e + 1];
    float n0 = d * dis[c0.x], n1 = d * dis[c1.x];
    float x0 = xw[(size_t)c0.x * 64 + lane];
    float x1 = xw[(size_t)c1.x * 64 + lane];
    acc = fmaf(n0, x0, acc);
    acc = fmaf(n1, x1, acc);
  }
  if (e < off1) {
    int2 c0 = csr[e];
    acc = fmaf(d * dis[c0.x], xw[(size_t)c0.x * 64 + lane], acc);
  }
  h[(size_t)node * 64 + lane] = fmaxf(acc, 0.f);
}

// ---------------- finalize: A = h@W1a (in place over h), B = h@W1b + b1 ------------
__global__ __launch_bounds__(256) void k_finalize(
    const float* __restrict__ mlp_w1, const float* __restrict__ mlp_b1,
    float* __restrict__ hA, float* __restrict__ Bb) {
  __shared__ float wa[FLAT];
  __shared__ float wb[FLAT];
  for (int i = threadIdx.x; i < FLAT; i += 256) {
    wa[i] = mlp_w1[i];
    wb[i] = mlp_w1[FLAT + i];
  }
  __syncthreads();
  const int lane = threadIdx.x & 15;
  const int grp = threadIdx.x >> 4;
  const int n0 = blockIdx.x * 64 + grp * 4;
  if (n0 >= NN) return;
  const int nvalid = (NN - n0 < 4) ? (NN - n0) : 4;
  const float4 b1v = ((const float4*)mlp_b1)[lane];   // fold b1 into B once
  const float4* hp[4];
#pragma unroll
  for (int m = 0; m < 4; ++m) {
    int n = (m < nvalid) ? (n0 + m) : n0;
    hp[m] = (const float4*)(hA + (size_t)n * 64);
  }
  float4 aA[4], aB[4];
#pragma unroll
  for (int m = 0; m < 4; ++m) { aA[m] = make_float4(0,0,0,0); aB[m] = make_float4(0,0,0,0); }
#pragma unroll
  for (int q = 0; q < 16; ++q) {
    const float* war = &wa[(q * 4) * 64 + lane * 4];
    const float* wbr = &wb[(q * 4) * 64 + lane * 4];
    float4 wa0 = *(const float4*)&war[0];
    float4 wa1 = *(const float4*)&war[64];
    float4 wa2 = *(const float4*)&war[128];
    float4 wa3 = *(const float4*)&war[192];
    float4 wb0 = *(const float4*)&wbr[0];
    float4 wb1 = *(const float4*)&wbr[64];
    float4 wb2 = *(const float4*)&wbr[128];
    float4 wb3 = *(const float4*)&wbr[192];
#pragma unroll
    for (int m = 0; m < 4; ++m) {
      float4 h4 = hp[m][q];
      fma4(aA[m], h4.x, wa0); fma4(aA[m], h4.y, wa1); fma4(aA[m], h4.z, wa2); fma4(aA[m], h4.w, wa3);
      fma4(aB[m], h4.x, wb0); fma4(aB[m], h4.y, wb1); fma4(aB[m], h4.z, wb2); fma4(aB[m], h4.w, wb3);
    }
  }
  for (int m = 0; m < nvalid; ++m) {
    *(float4*)&hA[(size_t)(n0 + m) * 64 + lane * 4] = aA[m];   // wave-lockstep: reads done
    float4 bo = aB[m];
    bo.x += b1v.x; bo.y += b1v.y; bo.z += b1v.z; bo.w += b1v.w;
    *(float4*)&Bb[(size_t)(n0 + m) * 64 + lane * 4] = bo;
  }
}

// ---------------- pass 2: edge MLP, edge-parallel, 4 edges per wave ----------------
// Edges processed in ORIGINAL order: eattr reads stream sequentially (was the
// dominant random-access HBM traffic), out[] writes stream sequentially (was a
// 52 MB scatter for 6.4 MB of data). All 8 A/B gathers + 16 eattr float4 loads
// issued up front -> 4x the memory-level parallelism of the old serial CSR walk.
// Bb already contains B + b1 (folded in k_finalize).
__global__ __launch_bounds__(256) void k_emlp(
    const int* __restrict__ ei, const float* __restrict__ A,
    const float* __restrict__ Bb, const float* __restrict__ eattr,
    const float* __restrict__ mlp_w1, const float* __restrict__ mlp_w2,
    const float* __restrict__ mlp_b2, float* __restrict__ out) {
  const int lane = threadIdx.x & 63;
  const int e0 = (blockIdx.x * 4 + (threadIdx.x >> 6)) * 4;
  if (e0 >= NE) return;
  float wc[16];
#pragma unroll
  for (int f = 0; f < 16; ++f) wc[f] = mlp_w1[(size_t)(128 + f) * 64 + lane];
  const float w2l = mlp_w2[lane];
  const float b2v = mlp_b2[0];
  const int4 rows = *(const int4*)&ei[e0];        // broadcast (uniform addr)
  const int4 cols = *(const int4*)&ei[NE + e0];
  // issue all gathers up front (independent -> deep MLP)
  const float av0 = A[(size_t)rows.x * 64 + lane], bv0 = Bb[(size_t)cols.x * 64 + lane];
  const float av1 = A[(size_t)rows.y * 64 + lane], bv1 = Bb[(size_t)cols.y * 64 + lane];
  const float av2 = A[(size_t)rows.z * 64 + lane], bv2 = Bb[(size_t)cols.z * 64 + lane];
  const float av3 = A[(size_t)rows.w * 64 + lane], bv3 = Bb[(size_t)cols.w * 64 + lane];
  const float4* ep = (const float4*)(eattr + (size_t)e0 * 16);
  float4 E00 = ep[0],  E01 = ep[1],  E02 = ep[2],  E03 = ep[3];
  float4 E10 = ep[4],  E11 = ep[5],  E12 = ep[6],  E13 = ep[7];
  float4 E20 = ep[8],  E21 = ep[9],  E22 = ep[10], E23 = ep[11];
  float4 E30 = ep[12], E31 = ep[13], E32 = ep[14], E33 = ep[15];

#define EDOT(acc, Ea, Eb, Ec, Ed)                                    \
  acc = fmaf(Ea.x, wc[0], acc);  acc = fmaf(Ea.y, wc[1], acc);       \
  acc = fmaf(Ea.z, wc[2], acc);  acc = fmaf(Ea.w, wc[3], acc);       \
  acc = fmaf(Eb.x, wc[4], acc);  acc = fmaf(Eb.y, wc[5], acc);       \
  acc = fmaf(Eb.z, wc[6], acc);  acc = fmaf(Eb.w, wc[7], acc);       \
  acc = fmaf(Ec.x, wc[8], acc);  acc = fmaf(Ec.y, wc[9], acc);       \
  acc = fmaf(Ec.z, wc[10], acc); acc = fmaf(Ec.w, wc[11], acc);      \
  acc = fmaf(Ed.x, wc[12], acc); acc = fmaf(Ed.y, wc[13], acc);      \
  acc = fmaf(Ed.z, wc[14], acc); acc = fmaf(Ed.w, wc[15], acc)

  float p0 = av0 + bv0; EDOT(p0, E00, E01, E02, E03); p0 = fmaxf(p0, 0.f) * w2l;
  float p1 = av1 + bv1; EDOT(p1, E10, E11, E12, E13); p1 = fmaxf(p1, 0.f) * w2l;
  float p2 = av2 + bv2; EDOT(p2, E20, E21, E22, E23); p2 = fmaxf(p2, 0.f) * w2l;
  float p3 = av3 + bv3; EDOT(p3, E30, E31, E32, E33); p3 = fmaxf(p3, 0.f) * w2l;
#undef EDOT

  // packed butterfly: 4 reductions in 10 shuffles; lane (l&3)==k ends with sum_k
  p0 += __shfl_xor(p0, 1); p1 += __shfl_xor(p1, 1);
  p2 += __shfl_xor(p2, 1); p3 += __shfl_xor(p3, 1);
  float q0 = (lane & 1) ? p1 : p0;
  float q1 = (lane & 1) ? p3 : p2;
  q0 += __shfl_xor(q0, 2); q1 += __shfl_xor(q1, 2);
  float r = (lane & 2) ? q1 : q0;
  r += __shfl_xor(r, 4);
  r += __shfl_xor(r, 8);
  r += __shfl_xor(r, 16);
  r += __shfl_xor(r, 32);
  if (lane < 4) out[e0 + lane] = r + b2v;        // sequential 16B store per wave
}

extern "C" void kernel_launch(void* const* d_in, const int* in_sizes, int n_in,
                              void* d_out, int out_size, void* d_ws, size_t ws_size,
                              hipStream_t stream) {
  (void)in_sizes; (void)n_in; (void)out_size; (void)ws_size;
  const float* x_seq  = (const float*)d_in[0];
  const float* eattr  = (const float*)d_in[1];
  const float* init_w = (const float*)d_in[2];
  const float* ode_w1 = (const float*)d_in[3];
  const float* ode_b1 = (const float*)d_in[4];
  const float* ode_w2 = (const float*)d_in[5];
  const float* ode_b2 = (const float*)d_in[6];
  const float* mlp_w1 = (const float*)d_in[7];
  const float* mlp_b1 = (const float*)d_in[8];
  const float* mlp_w2 = (const float*)d_in[9];
  const float* mlp_b2 = (const float*)d_in[10];
  const int*   eidx   = (const int*)d_in[11];
  float* out = (float*)d_out;

  float* ws   = (float*)d_ws;
  float* wbuf = ws;                          // [2][FLAT]
  float* kbuf = wbuf + 2 * FLAT;             // [2][4][FLAT]
  float* acc1 = kbuf + 8 * FLAT;             // [2][BN]
  float* WT   = acc1 + 2 * BN;               // [FLAT]
  float* dis  = ws + 49152;                  // [NN]
  int*   cnt  = (int*)(ws + 149152);         // [NN]
  int*   offs = (int*)(ws + 249152);         // [NN+1]
  int*   bsum = (int*)(ws + 349184);         // [512]
  int*   bofs = (int*)(ws + 349696);         // [512]
  int*   cur  = (int*)(ws + 350208);         // [NN]
  int2*  csr  = (int2*)(ws + 450560);        // [NE] (row, eid)
  float* xw   = ws + 450560 + 2 * (size_t)NE;  // [NN*64]; becomes B+b1 after finalize
  float* hA   = xw + (size_t)NN * 64;        // [NN*64]: h -> A in place
  // total ~66 MB of ws

  const int nblk_n = (NN + 255) / 256;       // 391

  k_init<<<128, 256, 0, stream>>>(init_w, wbuf, kbuf, acc1, cnt);
  k_hist<<<(NE + 255) / 256, 256, 0, stream>>>(eidx, cnt);
  k_scan1<<<nblk_n, 256, 0, stream>>>(cnt, offs, bsum);
  k_scan2<<<1, 512, 0, stream>>>(bsum, bofs, nblk_n);
  k_scan3<<<nblk_n, 256, 0, stream>>>(cnt, offs, bofs, cur, dis);
  k_fill<<<(NE + 255) / 256, 256, 0, stream>>>(eidx, cur, csr);

  const float h = 1.0f / 7.0f;
  for (int s = 0; s < 7; ++s) {
    int p = s & 1;
    for (int c = 0; c < 4; ++c) {
      int ev = s * 4 + c, pe = ev & 1;
      float c0, c1, c2, c3;
      const float* wb;
      float* wst = nullptr;
      int kp;
      if (c == 0) {          // k1 eval at w_next(prev step); also stores w[p]
        c0 = h * 0.125f; c1 = 3.f * h * 0.125f; c2 = c1; c3 = c0;
        wb = wbuf + (1 - p) * FLAT; kp = 1 - p; wst = wbuf + p * FLAT;
      } else if (c == 1) {   // w + h*k1/3
        c0 = h / 3.f; c1 = 0.f; c2 = 0.f; c3 = 0.f; wb = wbuf + p * FLAT; kp = p;
      } else if (c == 2) {   // w + h*(k2 - k1/3)
        c0 = -h / 3.f; c1 = h; c2 = 0.f; c3 = 0.f; wb = wbuf + p * FLAT; kp = p;
      } else {               // w + h*(k1 - k2 + k3)
        c0 = h; c1 = -h; c2 = h; c3 = 0.f; wb = wbuf + p * FLAT; kp = p;
      }
      k_odeA<<<256, 256, 0, stream>>>(ode_w1, wb, kbuf + (size_t)kp * 4 * FLAT,
                                      c0, c1, c2, c3,
                                      acc1 + pe * BN, acc1 + (1 - pe) * BN,
                                      kbuf + (size_t)(p * 4 + c) * FLAT, wst);
      k_odeB<<<256, 256, 0, stream>>>(ode_w2, acc1 + pe * BN, ode_b1, ode_b2,
                                      kbuf + (size_t)(p * 4 + c) * FLAT);
    }
  }
  k_final<<<16, 256, 0, stream>>>(wbuf, kbuf, WT);   // step 6 has parity 0

  k_xw<<<(NN + 63) / 64, 256, 0, stream>>>(x_seq + (size_t)(NT - 1) * NN * DIN, WT, xw);
  k_gh<<<(NN + 3) / 4, 256, 0, stream>>>(offs, csr, dis, xw, hA);
  k_finalize<<<(NN + 63) / 64, 256, 0, stream>>>(mlp_w1, mlp_b1, hA, xw); // A in hA, B+b1 in xw
  k_emlp<<<NE / 16, 256, 0, stream>>>(eidx, hA, xw, eattr,
                                      mlp_w1, mlp_w2, mlp_b2, out);
}

// Round 3
// 1146.052 us; speedup vs baseline: 1.3434x; 1.2019x over previous
//
#include <hip/hip_runtime.h>
#include <cstddef>

#define NT   8
#define NN   100000
#define NE   1600000
#define DIN  64
#define DH   64
#define DE   16
#define FLAT 4096
#define BN   1024

__device__ __forceinline__ void atomAdd(float* p, float v) { unsafeAtomicAdd(p, v); }

__device__ __forceinline__ void fma4(float4& a, float s, const float4& w) {
  a.x = fmaf(s, w.x, a.x); a.y = fmaf(s, w.y, a.y);
  a.z = fmaf(s, w.z, a.z); a.w = fmaf(s, w.w, a.w);
}

// ---------------- init: w[1]=init_w, zero k/acc1, zero cnt -------------------------
__global__ void k_init(const float* __restrict__ init_w, float* __restrict__ wbuf,
                       float* __restrict__ kbuf, float* __restrict__ acc1,
                       int* __restrict__ cnt) {
  int i = blockIdx.x * blockDim.x + threadIdx.x;          // 32768 threads
  if (i < FLAT) wbuf[FLAT + i] = init_w[i];
  if (i < 8 * FLAT) kbuf[i] = 0.f;
  if (i < 2 * BN) acc1[i] = 0.f;
  for (int n = i; n < NN; n += gridDim.x * blockDim.x) cnt[n] = 0;
}

// ---------------- ODE phase A: acc1[pe] += win @ w1 (tile-split, atomics) ----------
__global__ __launch_bounds__(256) void k_odeA(
    const float* __restrict__ w1, const float* __restrict__ wbase,
    const float* __restrict__ kbase, float c0, float c1, float c2, float c3,
    float* __restrict__ acc_dst, float* __restrict__ acc_zero,
    float* __restrict__ k_zero, float* __restrict__ w_store) {
  __shared__ float win[256];
  __shared__ float red[256];
  const int t = threadIdx.x;
  const int ic = blockIdx.x & 15, jc = blockIdx.x >> 4;   // 16 i-chunks x 16 j-chunks
  const int i0 = ic * 256;
  if (t < 16) k_zero[blockIdx.x * 16 + t] = 0.f;          // 256*16 = 4096
  if (t >= 16 && t < 20) acc_zero[blockIdx.x * 4 + (t - 16)] = 0.f;  // 256*4 = 1024
  {
    int i = i0 + t;
    float v = wbase[i] + c0 * kbase[i] + c1 * kbase[FLAT + i]
            + c2 * kbase[2 * FLAT + i] + c3 * kbase[3 * FLAT + i];
    win[t] = v;
    if (w_store != nullptr && jc == 0) w_store[i] = v;    // single-writer w_next
  }
  __syncthreads();
  const int jl = t & 63, ig = t >> 6;
  const int j = jc * 64 + jl;
  const float* wp = w1 + (size_t)(i0 + ig * 64) * BN + j;
  float acc = 0.f;
#pragma unroll 8
  for (int ii = 0; ii < 64; ++ii)
    acc = fmaf(win[ig * 64 + ii], wp[(size_t)ii * BN], acc);
  red[t] = acc;
  __syncthreads();
  if (t < 64) {
    float s = red[t] + red[t + 64] + red[t + 128] + red[t + 192];
    atomAdd(&acc_dst[jc * 64 + t], s);
  }
}

// ---------------- ODE phase B: k_dst += tanh(acc1+b1) @ w2 (+b2 once) --------------
__global__ __launch_bounds__(256) void k_odeB(
    const float* __restrict__ w2, const float* __restrict__ acc_src,
    const float* __restrict__ b1, const float* __restrict__ b2,
    float* __restrict__ k_dst) {
  __shared__ float tl[64];
  const int t = threadIdx.x;
  const int ic = blockIdx.x & 15, jc = blockIdx.x >> 4;
  const int i0 = ic * 64;
  if (t < 64) tl[t] = tanhf(acc_src[i0 + t] + b1[i0 + t]);
  __syncthreads();
  const int j = jc * 256 + t;
  const float* wp = w2 + (size_t)i0 * FLAT + j;
  float acc = (ic == 0) ? b2[j] : 0.f;
#pragma unroll 8
  for (int ii = 0; ii < 64; ++ii)
    acc = fmaf(tl[ii], wp[(size_t)ii * FLAT], acc);
  atomAdd(&k_dst[j], acc);
}

// ---------------- final W_T ---------------------------------------------------------
__global__ void k_final(const float* __restrict__ w0, const float* __restrict__ k0,
                        float* __restrict__ WT) {
  int i = blockIdx.x * blockDim.x + threadIdx.x;
  if (i < FLAT) {
    const float h8 = (1.0f / 7.0f) * 0.125f;
    WT[i] = w0[i] + h8 * (k0[i] + 3.f * (k0[FLAT + i] + k0[2 * FLAT + i]) + k0[3 * FLAT + i]);
  }
}

// ---------------- CSR build: histogram by col --------------------------------------
__global__ void k_hist(const int* __restrict__ ei, int* __restrict__ cnt) {
  int e = blockIdx.x * blockDim.x + threadIdx.x;
  if (e < NE) atomicAdd(&cnt[ei[NE + e]], 1);
}

// ---------------- scan step 1: per-block exclusive scan of cnt ---------------------
__global__ __launch_bounds__(256) void k_scan1(const int* __restrict__ cnt,
                                               int* __restrict__ offs,
                                               int* __restrict__ bsum) {
  __shared__ int s[256];
  const int t = threadIdx.x;
  const int i = blockIdx.x * 256 + t;
  int v = (i < NN) ? cnt[i] : 0;
  s[t] = v;
  __syncthreads();
  for (int off = 1; off < 256; off <<= 1) {
    int x = (t >= off) ? s[t - off] : 0;
    __syncthreads();
    s[t] += x;
    __syncthreads();
  }
  if (i < NN) offs[i] = s[t] - v;          // exclusive
  if (t == 255) bsum[blockIdx.x] = s[255];
}

// ---------------- scan step 2: scan of block sums (single block) -------------------
__global__ __launch_bounds__(512) void k_scan2(int* __restrict__ bsum,
                                               int* __restrict__ bofs, int nblk) {
  __shared__ int s[512];
  const int t = threadIdx.x;
  int v = (t < nblk) ? bsum[t] : 0;
  s[t] = v;
  __syncthreads();
  for (int off = 1; off < 512; off <<= 1) {
    int x = (t >= off) ? s[t - off] : 0;
    __syncthreads();
    s[t] += x;
    __syncthreads();
  }
  if (t < nblk) bofs[t] = s[t] - v;        // exclusive
}

// ---------------- scan step 3: add block offsets, init cursors, dis ----------------
__global__ __launch_bounds__(256) void k_scan3(const int* __restrict__ cnt,
                                               int* __restrict__ offs,
                                               const int* __restrict__ bofs,
                                               int* __restrict__ cur,
                                               float* __restrict__ dis) {
  const int i = blockIdx.x * 256 + threadIdx.x;
  if (i < NN) {
    int o = offs[i] + bofs[i >> 8];
    offs[i] = o;
    cur[i] = o;
    dis[i] = rsqrtf((float)(cnt[i] + 1));  // +1 self-loop, deg >= 1 always
  }
  if (i == 0) offs[NN] = NE;
}

// ---------------- CSR fill: csr[pos] = (row, edge_id), bucketed by col -------------
__global__ void k_fill(const int* __restrict__ ei, int* __restrict__ cur,
                       int2* __restrict__ csr) {
  int e = blockIdx.x * blockDim.x + threadIdx.x;
  if (e < NE) {
    int row = ei[e], col = ei[NE + e];
    int pos = atomicAdd(&cur[col], 1);
    csr[pos] = make_int2(row, e);
  }
}

// ---------------- xw = x_last @ W_T : 16 lanes/node, 4 nodes/thread-group ----------
__global__ __launch_bounds__(256) void k_xw(
    const float* __restrict__ x_last, const float* __restrict__ WT,
    float* __restrict__ xw) {
  __shared__ float wt[FLAT];
  for (int i = threadIdx.x; i < FLAT; i += 256) wt[i] = WT[i];
  __syncthreads();
  const int lane = threadIdx.x & 15;
  const int grp = threadIdx.x >> 4;
  const int n0 = blockIdx.x * 64 + grp * 4;
  if (n0 >= NN) return;
  const int nvalid = (NN - n0 < 4) ? (NN - n0) : 4;
  const float4* xp[4];
#pragma unroll
  for (int m = 0; m < 4; ++m) {
    int n = (m < nvalid) ? (n0 + m) : n0;
    xp[m] = (const float4*)(x_last + (size_t)n * 64);
  }
  float4 acc[4];
#pragma unroll
  for (int m = 0; m < 4; ++m) acc[m] = make_float4(0.f, 0.f, 0.f, 0.f);
#pragma unroll
  for (int q = 0; q < 16; ++q) {
    const float* wr = &wt[(q * 4) * 64 + lane * 4];
    float4 w0 = *(const float4*)&wr[0];
    float4 w1 = *(const float4*)&wr[64];
    float4 w2 = *(const float4*)&wr[128];
    float4 w3 = *(const float4*)&wr[192];
#pragma unroll
    for (int m = 0; m < 4; ++m) {
      float4 x4 = xp[m][q];          // same addr across 16 lanes -> broadcast
      fma4(acc[m], x4.x, w0); fma4(acc[m], x4.y, w1);
      fma4(acc[m], x4.z, w2); fma4(acc[m], x4.w, w3);
    }
  }
  for (int m = 0; m < nvalid; ++m)
    *(float4*)&xw[(size_t)(n0 + m) * 64 + lane * 4] = acc[m];
}

// ---------------- pass 1: h[col] = relu(sum_e norm*xw[row] + d^2*xw[col]) ----------
// one 64-lane wave per node, lane = feature index; pure gather, no atomics.
// 4-wide unroll: 4 csr entries + 4 xw gathers + 4 dis gathers issued per iteration
// (halves the dependent-latency chain count vs 2-wide). Single fmaf chain in edge
// order -> numerics identical to the serial walk.
__global__ __launch_bounds__(256) void k_gh(
    const int* __restrict__ offs, const int2* __restrict__ csr,
    const float* __restrict__ dis, const float* __restrict__ xw,
    float* __restrict__ h) {
  const int node = blockIdx.x * 4 + (threadIdx.x >> 6);
  const int lane = threadIdx.x & 63;
  if (node >= NN) return;
  const int off0 = offs[node], off1 = offs[node + 1];
  const float d = dis[node];
  float acc = d * d * xw[(size_t)node * 64 + lane];
  int e = off0;
  for (; e + 3 < off1; e += 4) {
    int2 c0 = csr[e], c1 = csr[e + 1], c2 = csr[e + 2], c3 = csr[e + 3];
    float x0 = xw[(size_t)c0.x * 64 + lane];
    float x1 = xw[(size_t)c1.x * 64 + lane];
    float x2 = xw[(size_t)c2.x * 64 + lane];
    float x3 = xw[(size_t)c3.x * 64 + lane];
    float n0 = d * dis[c0.x], n1 = d * dis[c1.x];
    float n2 = d * dis[c2.x], n3 = d * dis[c3.x];
    acc = fmaf(n0, x0, acc);
    acc = fmaf(n1, x1, acc);
    acc = fmaf(n2, x2, acc);
    acc = fmaf(n3, x3, acc);
  }
  for (; e < off1; ++e) {
    int2 c0 = csr[e];
    acc = fmaf(d * dis[c0.x], xw[(size_t)c0.x * 64 + lane], acc);
  }
  h[(size_t)node * 64 + lane] = fmaxf(acc, 0.f);
}

// ---------------- finalize: A = h@W1a (in place over h), B = h@W1b + b1 ------------
__global__ __launch_bounds__(256) void k_finalize(
    const float* __restrict__ mlp_w1, const float* __restrict__ mlp_b1,
    float* __restrict__ hA, float* __restrict__ Bb) {
  __shared__ float wa[FLAT];
  __shared__ float wb[FLAT];
  for (int i = threadIdx.x; i < FLAT; i += 256) {
    wa[i] = mlp_w1[i];
    wb[i] = mlp_w1[FLAT + i];
  }
  __syncthreads();
  const int lane = threadIdx.x & 15;
  const int grp = threadIdx.x >> 4;
  const int n0 = blockIdx.x * 64 + grp * 4;
  if (n0 >= NN) return;
  const int nvalid = (NN - n0 < 4) ? (NN - n0) : 4;
  const float4 b1v = ((const float4*)mlp_b1)[lane];   // fold b1 into B once
  const float4* hp[4];
#pragma unroll
  for (int m = 0; m < 4; ++m) {
    int n = (m < nvalid) ? (n0 + m) : n0;
    hp[m] = (const float4*)(hA + (size_t)n * 64);
  }
  float4 aA[4], aB[4];
#pragma unroll
  for (int m = 0; m < 4; ++m) { aA[m] = make_float4(0,0,0,0); aB[m] = make_float4(0,0,0,0); }
#pragma unroll
  for (int q = 0; q < 16; ++q) {
    const float* war = &wa[(q * 4) * 64 + lane * 4];
    const float* wbr = &wb[(q * 4) * 64 + lane * 4];
    float4 wa0 = *(const float4*)&war[0];
    float4 wa1 = *(const float4*)&war[64];
    float4 wa2 = *(const float4*)&war[128];
    float4 wa3 = *(const float4*)&war[192];
    float4 wb0 = *(const float4*)&wbr[0];
    float4 wb1 = *(const float4*)&wbr[64];
    float4 wb2 = *(const float4*)&wbr[128];
    float4 wb3 = *(const float4*)&wbr[192];
#pragma unroll
    for (int m = 0; m < 4; ++m) {
      float4 h4 = hp[m][q];
      fma4(aA[m], h4.x, wa0); fma4(aA[m], h4.y, wa1); fma4(aA[m], h4.z, wa2); fma4(aA[m], h4.w, wa3);
      fma4(aB[m], h4.x, wb0); fma4(aB[m], h4.y, wb1); fma4(aB[m], h4.z, wb2); fma4(aB[m], h4.w, wb3);
    }
  }
  for (int m = 0; m < nvalid; ++m) {
    *(float4*)&hA[(size_t)(n0 + m) * 64 + lane * 4] = aA[m];   // wave-lockstep: reads done
    float4 bo = aB[m];
    bo.x += b1v.x; bo.y += b1v.y; bo.z += b1v.z; bo.w += b1v.w;
    *(float4*)&Bb[(size_t)(n0 + m) * 64 + lane * 4] = bo;
  }
}

// ---------------- pass 2: edge MLP, edge-parallel, 8 edges per wave ----------------
// All 16 A/B gathers (the random long-latency loads; only 16 VGPRs) are issued
// before ANY compute. eattr/out stream sequentially. E-values consumed in two
// 4-edge halves so the register file isn't blown (VGPR=36 last round proved the
// compiler couldn't keep 4 edges' loads live). readfirstlane makes e0 provably
// wave-uniform so rows/cols/eattr loads can become scalar (SGPR) loads.
__global__ __launch_bounds__(256) void k_emlp(
    const int* __restrict__ ei, const float* __restrict__ A,
    const float* __restrict__ Bb, const float* __restrict__ eattr,
    const float* __restrict__ mlp_w1, const float* __restrict__ mlp_w2,
    const float* __restrict__ mlp_b2, float* __restrict__ out) {
  const int lane = threadIdx.x & 63;
  const int e0 = __builtin_amdgcn_readfirstlane((blockIdx.x * 4 + (threadIdx.x >> 6)) * 8);
  if (e0 >= NE) return;
  float wc[16];
#pragma unroll
  for (int f = 0; f < 16; ++f) wc[f] = mlp_w1[(size_t)(128 + f) * 64 + lane];
  const float w2l = mlp_w2[lane];
  const float b2v = mlp_b2[0];
  const int4 r01 = *(const int4*)&ei[e0];            // uniform -> s_load
  const int4 r23 = *(const int4*)&ei[e0 + 4];
  const int4 c01 = *(const int4*)&ei[NE + e0];
  const int4 c23 = *(const int4*)&ei[NE + e0 + 4];
  // ---- all 16 random gathers in flight before any compute (16 VGPRs) ----
  const float av0 = A[(size_t)r01.x * 64 + lane], bv0 = Bb[(size_t)c01.x * 64 + lane];
  const float av1 = A[(size_t)r01.y * 64 + lane], bv1 = Bb[(size_t)c01.y * 64 + lane];
  const float av2 = A[(size_t)r01.z * 64 + lane], bv2 = Bb[(size_t)c01.z * 64 + lane];
  const float av3 = A[(size_t)r01.w * 64 + lane], bv3 = Bb[(size_t)c01.w * 64 + lane];
  const float av4 = A[(size_t)r23.x * 64 + lane], bv4 = Bb[(size_t)c23.x * 64 + lane];
  const float av5 = A[(size_t)r23.y * 64 + lane], bv5 = Bb[(size_t)c23.y * 64 + lane];
  const float av6 = A[(size_t)r23.z * 64 + lane], bv6 = Bb[(size_t)c23.z * 64 + lane];
  const float av7 = A[(size_t)r23.w * 64 + lane], bv7 = Bb[(size_t)c23.w * 64 + lane];
  const float4* ep = (const float4*)(eattr + (size_t)e0 * 16);  // uniform base

#define EDOT(acc, Ea, Eb, Ec, Ed)                                    \
  acc = fmaf(Ea.x, wc[0], acc);  acc = fmaf(Ea.y, wc[1], acc);       \
  acc = fmaf(Ea.z, wc[2], acc);  acc = fmaf(Ea.w, wc[3], acc);       \
  acc = fmaf(Eb.x, wc[4], acc);  acc = fmaf(Eb.y, wc[5], acc);       \
  acc = fmaf(Eb.z, wc[6], acc);  acc = fmaf(Eb.w, wc[7], acc);       \
  acc = fmaf(Ec.x, wc[8], acc);  acc = fmaf(Ec.y, wc[9], acc);       \
  acc = fmaf(Ec.z, wc[10], acc); acc = fmaf(Ec.w, wc[11], acc);      \
  acc = fmaf(Ed.x, wc[12], acc); acc = fmaf(Ed.y, wc[13], acc);      \
  acc = fmaf(Ed.z, wc[14], acc); acc = fmaf(Ed.w, wc[15], acc)

  float p0, p1, p2, p3, p4, p5, p6, p7;
  {  // half 0: edges 0-3
    float4 E00 = ep[0],  E01 = ep[1],  E02 = ep[2],  E03 = ep[3];
    float4 E10 = ep[4],  E11 = ep[5],  E12 = ep[6],  E13 = ep[7];
    float4 E20 = ep[8],  E21 = ep[9],  E22 = ep[10], E23 = ep[11];
    float4 E30 = ep[12], E31 = ep[13], E32 = ep[14], E33 = ep[15];
    p0 = av0 + bv0; EDOT(p0, E00, E01, E02, E03); p0 = fmaxf(p0, 0.f) * w2l;
    p1 = av1 + bv1; EDOT(p1, E10, E11, E12, E13); p1 = fmaxf(p1, 0.f) * w2l;
    p2 = av2 + bv2; EDOT(p2, E20, E21, E22, E23); p2 = fmaxf(p2, 0.f) * w2l;
    p3 = av3 + bv3; EDOT(p3, E30, E31, E32, E33); p3 = fmaxf(p3, 0.f) * w2l;
  }
  {  // half 1: edges 4-7
    float4 E00 = ep[16], E01 = ep[17], E02 = ep[18], E03 = ep[19];
    float4 E10 = ep[20], E11 = ep[21], E12 = ep[22], E13 = ep[23];
    float4 E20 = ep[24], E21 = ep[25], E22 = ep[26], E23 = ep[27];
    float4 E30 = ep[28], E31 = ep[29], E32 = ep[30], E33 = ep[31];
    p4 = av4 + bv4; EDOT(p4, E00, E01, E02, E03); p4 = fmaxf(p4, 0.f) * w2l;
    p5 = av5 + bv5; EDOT(p5, E10, E11, E12, E13); p5 = fmaxf(p5, 0.f) * w2l;
    p6 = av6 + bv6; EDOT(p6, E20, E21, E22, E23); p6 = fmaxf(p6, 0.f) * w2l;
    p7 = av7 + bv7; EDOT(p7, E30, E31, E32, E33); p7 = fmaxf(p7, 0.f) * w2l;
  }
#undef EDOT

  // packed butterfly: 8 reductions in 17 shuffles; lane l (<8) ends with edge l sum
  p0 += __shfl_xor(p0, 1); p1 += __shfl_xor(p1, 1);
  p2 += __shfl_xor(p2, 1); p3 += __shfl_xor(p3, 1);
  p4 += __shfl_xor(p4, 1); p5 += __shfl_xor(p5, 1);
  p6 += __shfl_xor(p6, 1); p7 += __shfl_xor(p7, 1);
  float u0 = (lane & 1) ? p1 : p0;
  float u1 = (lane & 1) ? p3 : p2;
  float u2 = (lane & 1) ? p5 : p4;
  float u3 = (lane & 1) ? p7 : p6;
  u0 += __shfl_xor(u0, 2); u1 += __shfl_xor(u1, 2);
  u2 += __shfl_xor(u2, 2); u3 += __shfl_xor(u3, 2);
  float v0 = (lane & 2) ? u1 : u0;
  float v1 = (lane & 2) ? u3 : u2;
  v0 += __shfl_xor(v0, 4); v1 += __shfl_xor(v1, 4);
  float s = (lane & 4) ? v1 : v0;
  s += __shfl_xor(s, 8);
  s += __shfl_xor(s, 16);
  s += __shfl_xor(s, 32);
  if (lane < 8) out[e0 + lane] = s + b2v;        // sequential 32B store per wave
}

extern "C" void kernel_launch(void* const* d_in, const int* in_sizes, int n_in,
                              void* d_out, int out_size, void* d_ws, size_t ws_size,
                              hipStream_t stream) {
  (void)in_sizes; (void)n_in; (void)out_size; (void)ws_size;
  const float* x_seq  = (const float*)d_in[0];
  const float* eattr  = (const float*)d_in[1];
  const float* init_w = (const float*)d_in[2];
  const float* ode_w1 = (const float*)d_in[3];
  const float* ode_b1 = (const float*)d_in[4];
  const float* ode_w2 = (const float*)d_in[5];
  const float* ode_b2 = (const float*)d_in[6];
  const float* mlp_w1 = (const float*)d_in[7];
  const float* mlp_b1 = (const float*)d_in[8];
  const float* mlp_w2 = (const float*)d_in[9];
  const float* mlp_b2 = (const float*)d_in[10];
  const int*   eidx   = (const int*)d_in[11];
  float* out = (float*)d_out;

  float* ws   = (float*)d_ws;
  float* wbuf = ws;                          // [2][FLAT]
  float* kbuf = wbuf + 2 * FLAT;             // [2][4][FLAT]
  float* acc1 = kbuf + 8 * FLAT;             // [2][BN]
  float* WT   = acc1 + 2 * BN;               // [FLAT]
  float* dis  = ws + 49152;                  // [NN]
  int*   cnt  = (int*)(ws + 149152);         // [NN]
  int*   offs = (int*)(ws + 249152);         // [NN+1]
  int*   bsum = (int*)(ws + 349184);         // [512]
  int*   bofs = (int*)(ws + 349696);         // [512]
  int*   cur  = (int*)(ws + 350208);         // [NN]
  int2*  csr  = (int2*)(ws + 450560);        // [NE] (row, eid)
  float* xw   = ws + 450560 + 2 * (size_t)NE;  // [NN*64]; becomes B+b1 after finalize
  float* hA   = xw + (size_t)NN * 64;        // [NN*64]: h -> A in place
  // total ~66 MB of ws

  const int nblk_n = (NN + 255) / 256;       // 391

  k_init<<<128, 256, 0, stream>>>(init_w, wbuf, kbuf, acc1, cnt);
  k_hist<<<(NE + 255) / 256, 256, 0, stream>>>(eidx, cnt);
  k_scan1<<<nblk_n, 256, 0, stream>>>(cnt, offs, bsum);
  k_scan2<<<1, 512, 0, stream>>>(bsum, bofs, nblk_n);
  k_scan3<<<nblk_n, 256, 0, stream>>>(cnt, offs, bofs, cur, dis);
  k_fill<<<(NE + 255) / 256, 256, 0, stream>>>(eidx, cur, csr);

  const float h = 1.0f / 7.0f;
  for (int s = 0; s < 7; ++s) {
    int p = s & 1;
    for (int c = 0; c < 4; ++c) {
      int ev = s * 4 + c, pe = ev & 1;
      float c0, c1, c2, c3;
      const float* wb;
      float* wst = nullptr;
      int kp;
      if (c == 0) {          // k1 eval at w_next(prev step); also stores w[p]
        c0 = h * 0.125f; c1 = 3.f * h * 0.125f; c2 = c1; c3 = c0;
        wb = wbuf + (1 - p) * FLAT; kp = 1 - p; wst = wbuf + p * FLAT;
      } else if (c == 1) {   // w + h*k1/3
        c0 = h / 3.f; c1 = 0.f; c2 = 0.f; c3 = 0.f; wb = wbuf + p * FLAT; kp = p;
      } else if (c == 2) {   // w + h*(k2 - k1/3)
        c0 = -h / 3.f; c1 = h; c2 = 0.f; c3 = 0.f; wb = wbuf + p * FLAT; kp = p;
      } else {               // w + h*(k1 - k2 + k3)
        c0 = h; c1 = -h; c2 = h; c3 = 0.f; wb = wbuf + p * FLAT; kp = p;
      }
      k_odeA<<<256, 256, 0, stream>>>(ode_w1, wb, kbuf + (size_t)kp * 4 * FLAT,
                                      c0, c1, c2, c3,
                                      acc1 + pe * BN, acc1 + (1 - pe) * BN,
                                      kbuf + (size_t)(p * 4 + c) * FLAT, wst);
      k_odeB<<<256, 256, 0, stream>>>(ode_w2, acc1 + pe * BN, ode_b1, ode_b2,
                                      kbuf + (size_t)(p * 4 + c) * FLAT);
    }
  }
  k_final<<<16, 256, 0, stream>>>(wbuf, kbuf, WT);   // step 6 has parity 0

  k_xw<<<(NN + 63) / 64, 256, 0, stream>>>(x_seq + (size_t)(NT - 1) * NN * DIN, WT, xw);
  k_gh<<<(NN + 3) / 4, 256, 0, stream>>>(offs, csr, dis, xw, hA);
  k_finalize<<<(NN + 63) / 64, 256, 0, stream>>>(mlp_w1, mlp_b1, hA, xw); // A in hA, B+b1 in xw
  k_emlp<<<NE / 32, 256, 0, stream>>>(eidx, hA, xw, eattr,
                                      mlp_w1, mlp_w2, mlp_b2, out);
}